// Round 9
// baseline (318.135 us; speedup 1.0000x reference)
//
#include <hip/hip_runtime.h>
#include <cstddef>
#include <cstdint>

#define EMB 1024
#define NH 16
#define HD 64
#define BATCH 4
#define SEQ 2048
#define MROWS (BATCH * SEQ)   // 8192

typedef __attribute__((ext_vector_type(8))) short bf16x8;   // 8 bf16 in 4 VGPRs
typedef __attribute__((ext_vector_type(4))) float f32x4;    // MFMA C/D

__device__ __forceinline__ unsigned short f2bf(float f) {   // RNE
    union { float f; unsigned int i; } c; c.f = f;
    return (unsigned short)((c.i + 0x7FFFu + ((c.i >> 16) & 1u)) >> 16);
}
__device__ __forceinline__ unsigned short f2bfr(float f) {  // round-half-up (cheap)
    union { float f; unsigned int i; } c; c.f = f;
    return (unsigned short)((c.i + 0x8000u) >> 16);
}

// async global->LDS, 16B per lane. LDS dest must be wave-uniform base; HW adds lane*16.
#define GLOAD_LDS16(gp, lp) __builtin_amdgcn_global_load_lds(                  \
    (const __attribute__((address_space(1))) void*)(gp),                       \
    (__attribute__((address_space(3))) void*)(lp), 16, 0, 0)

// ---------------------------------------------------------------------------
// fused fp32 -> bf16 (RNE) for x, W_kqv, W_proj in one launch
// ---------------------------------------------------------------------------
__global__ __launch_bounds__(256) void cvt_all(
    const float* __restrict__ x, const float* __restrict__ wk,
    const float* __restrict__ wp, unsigned short* __restrict__ xh,
    unsigned short* __restrict__ wkh, unsigned short* __restrict__ wph) {
    const int A = (BATCH * SEQ * EMB) / 4;
    const int B2 = (3 * EMB * EMB) / 4;
    const int C = (EMB * EMB) / 4;
    const int tot = A + B2 + C;
    const int stride = gridDim.x * blockDim.x;
    for (int i = blockIdx.x * blockDim.x + threadIdx.x; i < tot; i += stride) {
        const float* s; unsigned short* d; int j;
        if (i < A)            { s = x;  d = xh;  j = i; }
        else if (i < A + B2)  { s = wk; d = wkh; j = i - A; }
        else                  { s = wp; d = wph; j = i - A - B2; }
        const float4 v = ((const float4*)s)[j];
        ushort4 h;
        h.x = f2bf(v.x); h.y = f2bf(v.y); h.z = f2bf(v.z); h.w = f2bf(v.w);
        ((ushort4*)d)[j] = h;
    }
}

// ---------------------------------------------------------------------------
// Stage one 128x32 bf16 tile (linear [128][32]) via global_load_lds.
// ---------------------------------------------------------------------------
__device__ __forceinline__ void stage_tile(const unsigned short* __restrict__ src,
                                           int row0, int kt,
                                           unsigned short* lds, int wave, int lane) {
#pragma unroll
    for (int i = 0; i < 2; ++i) {
        const int c = wave * 2 + i;
        const int r = c * 16 + (lane >> 2);
        const int kq = (lane & 3) * 8;
        GLOAD_LDS16(src + (size_t)(row0 + r) * 1024 + kt + kq, lds + c * 512);
    }
}

// ---------------------------------------------------------------------------
// Shared 2-phase double-buffered GEMM mainloop: C[128,128] += A[M,1024]B^T.
// Stage k+1 into buf^1 BEFORE computing k; ONE barrier per K-step (its
// implicit vmcnt(0)/lgkmcnt(0) drain completes the in-flight stage and
// retires this step's frag reads across all waves).
// ---------------------------------------------------------------------------
__device__ __forceinline__ void gemm_2ph(const unsigned short* __restrict__ A,
                                         const unsigned short* __restrict__ B,
                                         unsigned short* As, unsigned short* Bs,
                                         int m0, int n0, int w, int lane,
                                         f32x4 (&acc)[4][4]) {
    const int wr = w >> 1, wc = w & 1;
    const int g8 = (lane >> 4) * 8, l15 = lane & 15;

    stage_tile(A, m0, 0, As, w, lane);
    stage_tile(B, n0, 0, Bs, w, lane);
    __syncthreads();                       // prologue stage complete

    int cur = 0;
    for (int kt = 0; kt < 1024; kt += 32) {
        const int nxt = cur ^ 1;
        if (kt + 32 < 1024) {              // issue next-tile loads (fly under MFMA)
            stage_tile(A, m0, kt + 32, As + nxt * 4096, w, lane);
            stage_tile(B, n0, kt + 32, Bs + nxt * 4096, w, lane);
        }
        const unsigned short* Ac = As + cur * 4096;
        const unsigned short* Bc = Bs + cur * 4096;
        bf16x8 a[4], bb[4];
#pragma unroll
        for (int m = 0; m < 4; ++m)
            a[m] = *(const bf16x8*)&Ac[(wr * 64 + m * 16 + l15) * 32 + g8];
#pragma unroll
        for (int n = 0; n < 4; ++n)
            bb[n] = *(const bf16x8*)&Bc[(wc * 64 + n * 16 + l15) * 32 + g8];
#pragma unroll
        for (int m = 0; m < 4; ++m)
#pragma unroll
            for (int n = 0; n < 4; ++n)
                acc[m][n] = __builtin_amdgcn_mfma_f32_16x16x32_bf16(a[m], bb[n], acc[m][n], 0, 0, 0);
        __syncthreads();                   // drains stage (vmcnt) + reads (lgkm)
        cur = nxt;
    }
}

// ---------------------------------------------------------------------------
// Kernel 1: kqv = x @ W^T + b, bf16 MFMA, 2-phase pipelined.
// ---------------------------------------------------------------------------
__global__ __launch_bounds__(256) void gemm_qkv_mfma(
    const unsigned short* __restrict__ xh, const unsigned short* __restrict__ wh,
    const float* __restrict__ bias,
    unsigned short* __restrict__ Ko, unsigned short* __restrict__ Qo,
    unsigned short* __restrict__ Vo) {
    __shared__ unsigned short As[2 * 128 * 32];
    __shared__ unsigned short Bs[2 * 128 * 32];

    const int t = threadIdx.x, lane = t & 63, w = t >> 6;
    const int wr = w >> 1, wc = w & 1;
    const int g4 = (lane >> 4) * 4, l15 = lane & 15;

    const int nwg = 64 * 24;                       // 1536, %8 == 0
    const int lin = blockIdx.x + gridDim.x * blockIdx.y;
    const int swz = (lin & 7) * (nwg >> 3) + (lin >> 3);
    const int m0 = (swz & 63) * 128, n0 = (swz >> 6) * 128;

    f32x4 acc[4][4] = {};
    gemm_2ph(xh, wh, As, Bs, m0, n0, w, lane, acc);

#pragma unroll
    for (int n = 0; n < 4; ++n) {
        const int col = n0 + wc * 64 + n * 16 + l15;   // [0,3072)
        const float bv = bias[col];
        const int which = col >> 10;
        unsigned short* outp = (which == 0) ? Ko : (which == 1 ? Qo : Vo);
        const int cm = col & 1023, h = cm >> 6, d = cm & 63;
#pragma unroll
        for (int m = 0; m < 4; ++m)
#pragma unroll
            for (int jj = 0; jj < 4; ++jj) {
                const int row = m0 + wr * 64 + m * 16 + g4 + jj;
                const int b = row >> 11, s = row & 2047;
                outp[(((size_t)(b * NH + h) * SEQ + s) << 6) + d] =
                    f2bf(acc[m][n][jj] + bv);
            }
    }
}

// ---------------------------------------------------------------------------
// Kernel 3: out = Y @ W_proj^T + b, bf16 MFMA, 2-phase pipelined, fp32 out
// ---------------------------------------------------------------------------
__global__ __launch_bounds__(256) void gemm_proj_mfma(
    const unsigned short* __restrict__ Yb, const unsigned short* __restrict__ wh,
    const float* __restrict__ bias, float* __restrict__ Out) {
    __shared__ unsigned short As[2 * 128 * 32];
    __shared__ unsigned short Bs[2 * 128 * 32];

    const int t = threadIdx.x, lane = t & 63, w = t >> 6;
    const int wr = w >> 1, wc = w & 1;
    const int g4 = (lane >> 4) * 4, l15 = lane & 15;

    const int nwg = 64 * 8;                        // 512
    const int lin = blockIdx.x + gridDim.x * blockIdx.y;
    const int swz = (lin & 7) * (nwg >> 3) + (lin >> 3);
    const int m0 = (swz & 63) * 128, n0 = (swz >> 6) * 128;

    f32x4 acc[4][4] = {};
    gemm_2ph(Yb, wh, As, Bs, m0, n0, w, lane, acc);

#pragma unroll
    for (int n = 0; n < 4; ++n) {
        const int col = n0 + wc * 64 + n * 16 + l15;
        const float bv = bias[col];
#pragma unroll
        for (int m = 0; m < 4; ++m)
#pragma unroll
            for (int jj = 0; jj < 4; ++jj) {
                const int row = m0 + wr * 64 + m * 16 + g4 + jj;
                Out[(size_t)row * EMB + col] = acc[m][n][jj] + bv;
            }
    }
}

// ---------------------------------------------------------------------------
// Kernel 2: causal flash attention, bf16 MFMA, swapped QK^T + streaming
// fixed-max softmax, split-PV (two kv-64 halves -> Ps[128][72]).
// LDS = 18432 + 17408 + 18432 = 54272 B -> 3 blocks/CU (x3 = 162816 <= 163840).
// Grid 512 (XCD-swizzled): block = (pair p, bh); q-tiles {p, 15-p} of 128 rows
// -> exactly 17 KV-128 iterations per block. 4 waves; wave w owns 32 q-rows.
// ---------------------------------------------------------------------------
__global__ __launch_bounds__(256, 3) void attn_mfma(
    const unsigned short* __restrict__ Kt, const unsigned short* __restrict__ Qt,
    const unsigned short* __restrict__ Vg, unsigned short* __restrict__ Y) {
    __shared__ unsigned short Ks[128][72];
    __shared__ unsigned short Vs[64][136];   // Vs[d][kv ^ (d&56)], kv 0..127
    __shared__ unsigned short Ps[128][72];   // P[q][kv-half], wave-private rows

    const int lin = blockIdx.x;              // 0..511
    const int swz = (lin & 7) * 64 + (lin >> 3);
    const int pair = swz & 7, bh = swz >> 3;
    const int b = bh >> 4, h = bh & 15;
    const unsigned short* Qp = Qt + ((size_t)bh * SEQ << 6);
    const unsigned short* Kp = Kt + ((size_t)bh * SEQ << 6);
    const unsigned short* Vp = Vg + ((size_t)bh * SEQ << 6);

    const int t = threadIdx.x, lane = t & 63, w = t >> 6;
    const int hi = lane >> 4, l15 = lane & 15, g8 = hi * 8;
    const float SCL = 0.125f * 1.44269504f;  // 1/sqrt(64) * log2(e)

    union U8 { uint4 q; unsigned short u[8]; };
    U8 kreg[4], vreg[4];
    auto loadKV = [&](int tile) {            // 128 KV rows into regs
#pragma unroll
        for (int i = 0; i < 4; ++i) {
            const int c = t + (i << 8);      // 0..1023
            const int r = c >> 3, col = (c & 7) * 8;
            kreg[i].q = *(const uint4*)(Kp + ((size_t)tile << 13) + r * 64 + col);
            vreg[i].q = *(const uint4*)(Vp + ((size_t)tile << 13) + r * 64 + col);
        }
    };

#pragma unroll 1
    for (int ph = 0; ph < 2; ++ph) {
        const int qt = ph ? (15 - pair) : pair;
        const int ntiles = qt + 1;
        const int q0 = qt * 128 + w * 32;    // wave's first q-row

        // Q fragments (B-operand): rows q0+rb*16+l15
        bf16x8 qf[2][2];
#pragma unroll
        for (int rb = 0; rb < 2; ++rb)
#pragma unroll
            for (int kc = 0; kc < 2; ++kc)
                qf[rb][kc] = *(const bf16x8*)(
                    Qp + ((size_t)(q0 + rb * 16 + l15) << 6) + kc * 32 + g8);

        float lsum[2] = {0.f, 0.f};
        f32x4 o_acc[2][4] = {};

        loadKV(0);
#pragma unroll 1
        for (int tile = 0; tile < ntiles; ++tile) {
            __syncthreads();   // prev iteration's LDS reads done
#pragma unroll
            for (int i = 0; i < 4; ++i) {
                const int c = t + (i << 8);
                const int r = c >> 3, col = (c & 7) * 8;
                *(uint4*)&Ks[r][col] = kreg[i].q;
#pragma unroll
                for (int j = 0; j < 8; ++j) {
                    const int d = col + j;
                    Vs[d][r ^ (d & 56)] = vreg[i].u[j];
                }
            }
            if (tile + 1 < ntiles) loadKV(tile + 1);   // prefetch (regs, no drain)
            __syncthreads();

            const bool diag = (tile == ntiles - 1);
            const int kvb = tile << 7;

            __builtin_amdgcn_s_setprio(1);
#pragma unroll
            for (int half = 0; half < 2; ++half) {
                // ---- S^T = K Q^T (kv-half) with streaming softmax ----
#pragma unroll
                for (int nn = 0; nn < 4; ++nn) {
                    const int n = half * 4 + nn;
                    const bf16x8 kf0 = *(const bf16x8*)&Ks[n * 16 + l15][g8];
                    const bf16x8 kf1 = *(const bf16x8*)&Ks[n * 16 + l15][32 + g8];
                    f32x4 t0 = {}, t1 = {};
                    t0 = __builtin_amdgcn_mfma_f32_16x16x32_bf16(kf0, qf[0][0], t0, 0, 0, 0);
                    t0 = __builtin_amdgcn_mfma_f32_16x16x32_bf16(kf1, qf[0][1], t0, 0, 0, 0);
                    t1 = __builtin_amdgcn_mfma_f32_16x16x32_bf16(kf0, qf[1][0], t1, 0, 0, 0);
                    t1 = __builtin_amdgcn_mfma_f32_16x16x32_bf16(kf1, qf[1][1], t1, 0, 0, 0);
#pragma unroll
                    for (int rb = 0; rb < 2; ++rb) {
                        const f32x4 tt = rb ? t1 : t0;
                        const int qrow = q0 + rb * 16 + l15;
                        unsigned int pk[2];
#pragma unroll
                        for (int jp = 0; jp < 2; ++jp) {
                            float v0 = fmaf(tt[2 * jp], SCL, -8.0f);
                            float v1 = fmaf(tt[2 * jp + 1], SCL, -8.0f);
                            if (diag) {
                                const int kv = kvb + n * 16 + 4 * hi + 2 * jp;
                                if (kv > qrow)     v0 = -1e30f;
                                if (kv + 1 > qrow) v1 = -1e30f;
                            }
                            const float p0 = exp2f(v0), p1 = exp2f(v1);
                            lsum[rb] += p0 + p1;
                            pk[jp] = (unsigned int)f2bfr(p0) |
                                     ((unsigned int)f2bfr(p1) << 16);
                        }
                        *(uint2*)&Ps[w * 32 + rb * 16 + l15][nn * 16 + 4 * hi] =
                            make_uint2(pk[0], pk[1]);
                    }
                }

                // ---- O += P_half V_half (same-wave DS: in-order per wave) ----
#pragma unroll
                for (int kc2 = 0; kc2 < 2; ++kc2) {
                    const int kc = half * 2 + kc2;
                    bf16x8 vf[4];
#pragma unroll
                    for (int nd = 0; nd < 4; ++nd) {
                        const int d = nd * 16 + l15;
                        vf[nd] = *(const bf16x8*)&Vs[d][(kc * 32 + g8) ^ (d & 56)];
                    }
                    const bf16x8 pf0 = *(const bf16x8*)&Ps[w * 32 + l15][kc2 * 32 + g8];
                    const bf16x8 pf1 = *(const bf16x8*)&Ps[w * 32 + 16 + l15][kc2 * 32 + g8];
#pragma unroll
                    for (int nd = 0; nd < 4; ++nd) {
                        o_acc[0][nd] = __builtin_amdgcn_mfma_f32_16x16x32_bf16(pf0, vf[nd], o_acc[0][nd], 0, 0, 0);
                        o_acc[1][nd] = __builtin_amdgcn_mfma_f32_16x16x32_bf16(pf1, vf[nd], o_acc[1][nd], 0, 0, 0);
                    }
                }
            }
            __builtin_amdgcn_s_setprio(0);
        }

        // epilogue: reduce l across hi-copies, O/l -> bf16 -> Y[B,S,E]
        // o_acc[rb][nd][jj] holds O[q = q0+rb*16+4*hi+jj][d = nd*16+l15]
#pragma unroll
        for (int rb = 0; rb < 2; ++rb) {
            float lv = lsum[rb];
            lv += __shfl_xor(lv, 16);
            lv += __shfl_xor(lv, 32);          // all lanes: l for q-row = l15
#pragma unroll
            for (int jj = 0; jj < 4; ++jj) {
                const float inv = 1.0f / __shfl(lv, 4 * hi + jj);
                const int srow = q0 + rb * 16 + 4 * hi + jj;
#pragma unroll
                for (int nd = 0; nd < 4; ++nd)
                    Y[((size_t)(b * SEQ + srow) << 10) + (h << 6) + nd * 16 + l15] =
                        f2bf(o_acc[rb][nd][jj] * inv);
            }
        }
    }
}

// ---------------------------------------------------------------------------
extern "C" void kernel_launch(void* const* d_in, const int* in_sizes, int n_in,
                              void* d_out, int out_size, void* d_ws, size_t ws_size,
                              hipStream_t stream) {
    const float* x  = (const float*)d_in[0];
    const float* Wk = (const float*)d_in[1];
    const float* bk = (const float*)d_in[2];
    const float* Wp = (const float*)d_in[3];
    const float* bp = (const float*)d_in[4];
    float* out = (float*)d_out;

    char* ws = (char*)d_ws;
    const size_t MB = 1024 * 1024;
    unsigned short* xh  = (unsigned short*)(ws + 0 * MB);
    unsigned short* wkh = (unsigned short*)(ws + 16 * MB);
    unsigned short* wph = (unsigned short*)(ws + 22 * MB);
    unsigned short* Ko  = (unsigned short*)(ws + 24 * MB);
    unsigned short* Qo  = (unsigned short*)(ws + 40 * MB);
    unsigned short* Vo  = (unsigned short*)(ws + 56 * MB);
    unsigned short* Yo  = (unsigned short*)(ws + 72 * MB);   // 88 MiB total

    cvt_all<<<2048, 256, 0, stream>>>(x, Wk, Wp, xh, wkh, wph);

    gemm_qkv_mfma<<<dim3(MROWS / 128, 3072 / 128), 256, 0, stream>>>(
        xh, wkh, bk, Ko, Qo, Vo);
    attn_mfma<<<512, 256, 0, stream>>>(Ko, Qo, Vo, Yo);
    gemm_proj_mfma<<<dim3(MROWS / 128, EMB / 128), 256, 0, stream>>>(
        Yo, wph, bp, out);
}